// Round 1
// baseline (6737.546 us; speedup 1.0000x reference)
//
#include <hip/hip_runtime.h>

// Decoder: 6x conv_transpose3d k=3, NDHWC, fp32.
// conv_transpose(SAME, transpose_kernel=False) == correlation over stride-dilated input:
//   stride 2: O[o] = sum_k W[k] * Xd[o+k-2],  Xd[p] = X[p/2] if p even & in range else 0
//   stride 1: O[o] = sum_k W[k] * X[o+k-1]    (standard SAME correlation)
// Weight layout DHWIO: W[kd][kh][kw][ci][co].

template<int STRIDE, bool RELU>
__global__ __launch_bounds__(256) void deconv_vec4(
    const float* __restrict__ x, const float* __restrict__ w,
    const float* __restrict__ b, float* __restrict__ y,
    int Din, int Cin, int Cout)
{
    const int Dout = Din * STRIDE;
    const int co4  = Cout >> 2;                    // float4 groups of output channels
    const int total = Dout * Dout * Dout * co4;
    int gid = blockIdx.x * blockDim.x + threadIdx.x;
    if (gid >= total) return;

    const int c  = (gid % co4) << 2;
    int sp       = gid / co4;
    const int ow = sp % Dout; sp /= Dout;
    const int oh = sp % Dout; sp /= Dout;
    const int od = sp;
    constexpr int PAD = (STRIDE == 2) ? 2 : 1;

    const float* bp = b + c;
    float4 acc = make_float4(bp[0], bp[1], bp[2], bp[3]);

    for (int kd = 0; kd < 3; ++kd) {
        const int pd = od + kd - PAD;
        if (pd < 0 || (STRIDE == 2 && (pd & 1)) || (pd / STRIDE) >= Din) continue;
        const int id = pd / STRIDE;
        for (int kh = 0; kh < 3; ++kh) {
            const int ph = oh + kh - PAD;
            if (ph < 0 || (STRIDE == 2 && (ph & 1)) || (ph / STRIDE) >= Din) continue;
            const int ih = ph / STRIDE;
            for (int kw = 0; kw < 3; ++kw) {
                const int pw = ow + kw - PAD;
                if (pw < 0 || (STRIDE == 2 && (pw & 1)) || (pw / STRIDE) >= Din) continue;
                const int iw = pw / STRIDE;
                const float* __restrict__ xp = x + ((id * Din + ih) * Din + iw) * Cin;
                const float* __restrict__ wp = w + ((kd * 3 + kh) * 3 + kw) * Cin * Cout + c;
                #pragma unroll 8
                for (int ci = 0; ci < Cin; ++ci) {
                    const float  xv = xp[ci];
                    const float4 wv = *(const float4*)(wp + ci * Cout);
                    acc.x = fmaf(xv, wv.x, acc.x);
                    acc.y = fmaf(xv, wv.y, acc.y);
                    acc.z = fmaf(xv, wv.z, acc.z);
                    acc.w = fmaf(xv, wv.w, acc.w);
                }
            }
        }
    }
    if (RELU) {
        acc.x = fmaxf(acc.x, 0.f); acc.y = fmaxf(acc.y, 0.f);
        acc.z = fmaxf(acc.z, 0.f); acc.w = fmaxf(acc.w, 0.f);
    }
    *(float4*)(y + ((od * Dout + oh) * Dout + ow) * Cout + c) = acc;
}

// Final layer: stride 1, Cin=64 -> Cout=3, no relu. One thread per (voxel, co).
__global__ __launch_bounds__(256) void deconv_c3(
    const float* __restrict__ x, const float* __restrict__ w,
    const float* __restrict__ b, float* __restrict__ y, int D, int Cin)
{
    const int total = D * D * D * 3;
    int gid = blockIdx.x * blockDim.x + threadIdx.x;
    if (gid >= total) return;
    const int co = gid % 3;
    int sp       = gid / 3;
    const int ow = sp % D; sp /= D;
    const int oh = sp % D; sp /= D;
    const int od = sp;

    float acc = b[co];
    for (int kd = 0; kd < 3; ++kd) {
        const int id = od + kd - 1;
        if (id < 0 || id >= D) continue;
        for (int kh = 0; kh < 3; ++kh) {
            const int ih = oh + kh - 1;
            if (ih < 0 || ih >= D) continue;
            for (int kw = 0; kw < 3; ++kw) {
                const int iw = ow + kw - 1;
                if (iw < 0 || iw >= D) continue;
                const float* xp = x + ((id * D + ih) * D + iw) * Cin;
                const float* wp = w + ((kd * 3 + kh) * 3 + kw) * Cin * 3 + co;
                #pragma unroll 4
                for (int ci = 0; ci < Cin; ++ci)
                    acc = fmaf(xp[ci], wp[ci * 3], acc);
            }
        }
    }
    y[((od * D + oh) * D + ow) * 3 + co] = acc;
}

extern "C" void kernel_launch(void* const* d_in, const int* in_sizes, int n_in,
                              void* d_out, int out_size, void* d_ws, size_t ws_size,
                              hipStream_t stream)
{
    const float* x   = (const float*)d_in[0];
    const float* w0  = (const float*)d_in[1];  const float* b0  = (const float*)d_in[2];
    const float* w00 = (const float*)d_in[3];  const float* b00 = (const float*)d_in[4];
    const float* w1  = (const float*)d_in[5];  const float* b1  = (const float*)d_in[6];
    const float* w10 = (const float*)d_in[7];  const float* b10 = (const float*)d_in[8];
    const float* w2  = (const float*)d_in[9];  const float* b2  = (const float*)d_in[10];
    const float* w20 = (const float*)d_in[11]; const float* b20 = (const float*)d_in[12];
    float* out = (float*)d_out;

    // Ping-pong workspace: A holds t0(2MB) -> t2(16MB) -> t4(64MB); B holds t1(2MB) -> t3(16MB).
    // Total d_ws use: (16777216 + 4194304) * 4 = 80 MiB.
    float* A = (float*)d_ws;
    float* B = A + 16777216;

    auto blocks = [](int total){ return (total + 255) / 256; };

    // L0: x(8^3 x128) --s2--> A(16^3 x128)
    deconv_vec4<2,false><<<blocks(16*16*16*32), 256, 0, stream>>>(x,   w0,  b0,  A, 8,  128, 128);
    // L1: A --s1+relu--> B(16^3 x128)
    deconv_vec4<1,true ><<<blocks(16*16*16*32), 256, 0, stream>>>(A,   w00, b00, B, 16, 128, 128);
    // L2: B --s2--> A(32^3 x128)
    deconv_vec4<2,false><<<blocks(32*32*32*32), 256, 0, stream>>>(B,   w1,  b1,  A, 16, 128, 128);
    // L3: A --s1+relu--> B(32^3 x128)
    deconv_vec4<1,true ><<<blocks(32*32*32*32), 256, 0, stream>>>(A,   w10, b10, B, 32, 128, 128);
    // L4: B --s2--> A(64^3 x64)
    deconv_vec4<2,false><<<blocks(64*64*64*16), 256, 0, stream>>>(B,   w2,  b2,  A, 32, 128, 64);
    // L5: A --s1--> out(64^3 x3)
    deconv_c3<<<blocks(64*64*64*3), 256, 0, stream>>>(A, w20, b20, out, 64, 64);
}

// Round 2
// 2640.599 us; speedup vs baseline: 2.5515x; 2.5515x over previous
//
#include <hip/hip_runtime.h>

// Decoder: 6x conv_transpose3d k=3, NDHWC, fp32.
//   stride 1 SAME: O[o] = sum_k W[k] * X[o+k-1]
//   stride 2 SAME: output parity r per dim selects taps:
//     r==1: single tap kd=1, id=i (always valid)
//     r==0: kd=2 -> id=i (valid), kd=0 -> id=i-1 (valid iff i>0)
//   where o = 2*i + r. Weight layout DHWIO: W[kd][kh][kw][ci][co].
//
// Design: lanes vary over spatial voxels only; the co-chunk is wave-uniform
// (forced with readfirstlane) so all weight/bias reads are s_load through the
// scalar cache, leaving the inner loop ~pure v_fma_f32. Boundary handling is
// clamped-address load + cndmask-zero to keep control flow uniform.

__device__ __forceinline__ int rfl(int v) { return __builtin_amdgcn_readfirstlane(v); }

template<int CO_CHUNK, bool RELU>
__global__ __launch_bounds__(256) void conv_s1(
    const float* __restrict__ x, const float* __restrict__ w,
    const float* __restrict__ b, float* __restrict__ y,
    int D, int lD, int Cin, int Cout)
{
    const int lane = threadIdx.x;                 // blockDim.x == 64
    const int vox  = blockIdx.x * 64 + lane;
    const int ow   = vox & (D - 1);
    const int oh   = (vox >> lD) & (D - 1);
    const int od   = vox >> (2 * lD);
    const int c0   = rfl((blockIdx.y * blockDim.y + threadIdx.y) * CO_CHUNK);

    float acc[CO_CHUNK];
    #pragma unroll
    for (int c = 0; c < CO_CHUNK; ++c) acc[c] = b[c0 + c];

    for (int kd = 0; kd < 3; ++kd) {
        const int id = od + kd - 1;
        const bool vd = (unsigned)id < (unsigned)D;
        const int idc = vd ? id : 0;
        for (int kh = 0; kh < 3; ++kh) {
            const int ih = oh + kh - 1;
            const bool vh = (unsigned)ih < (unsigned)D;
            const int ihc = vh ? ih : 0;
            for (int kw = 0; kw < 3; ++kw) {
                const int iw = ow + kw - 1;
                const bool vw = (unsigned)iw < (unsigned)D;
                const int iwc = vw ? iw : 0;
                const bool valid = vd && vh && vw;
                const float* __restrict__ xp = x + (size_t)((idc * D + ihc) * D + iwc) * Cin;
                const float* __restrict__ wp = w + (size_t)((kd * 3 + kh) * 3 + kw) * Cin * Cout + c0;
                for (int ci = 0; ci < Cin; ci += 4) {
                    float4 xv = *(const float4*)(xp + ci);
                    const float x0 = valid ? xv.x : 0.f;
                    const float x1 = valid ? xv.y : 0.f;
                    const float x2 = valid ? xv.z : 0.f;
                    const float x3 = valid ? xv.w : 0.f;
                    const float* __restrict__ wr = wp + (size_t)ci * Cout;
                    #pragma unroll
                    for (int c = 0; c < CO_CHUNK; ++c) acc[c] = fmaf(x0, wr[c], acc[c]);
                    wr += Cout;
                    #pragma unroll
                    for (int c = 0; c < CO_CHUNK; ++c) acc[c] = fmaf(x1, wr[c], acc[c]);
                    wr += Cout;
                    #pragma unroll
                    for (int c = 0; c < CO_CHUNK; ++c) acc[c] = fmaf(x2, wr[c], acc[c]);
                    wr += Cout;
                    #pragma unroll
                    for (int c = 0; c < CO_CHUNK; ++c) acc[c] = fmaf(x3, wr[c], acc[c]);
                }
            }
        }
    }

    float* __restrict__ yp = y + (size_t)vox * Cout + c0;
    #pragma unroll
    for (int c = 0; c < CO_CHUNK; ++c) if (RELU) acc[c] = fmaxf(acc[c], 0.f);
    #pragma unroll
    for (int c = 0; c < CO_CHUNK; c += 4)
        *(float4*)(yp + c) = make_float4(acc[c], acc[c + 1], acc[c + 2], acc[c + 3]);
}

template<int CO_CHUNK>
__global__ __launch_bounds__(256) void deconv_s2(
    const float* __restrict__ x, const float* __restrict__ w,
    const float* __restrict__ b, float* __restrict__ y,
    int Din, int lD, int Cin, int Cout)
{
    const int Dout = 2 * Din;
    const int lane = threadIdx.x;                 // blockDim.x == 64
    const int sv   = blockIdx.x * 64 + lane;      // sub-voxel in Din^3
    const int iwv  = sv & (Din - 1);
    const int ihv  = (sv >> lD) & (Din - 1);
    const int idv  = sv >> (2 * lD);
    const int par  = blockIdx.z;                  // parity (rd,rh,rw)
    const int rd = (par >> 2) & 1, rh = (par >> 1) & 1, rw = par & 1;
    const int od = 2 * idv + rd, oh = 2 * ihv + rh, ow = 2 * iwv + rw;
    const int c0 = rfl((blockIdx.y * blockDim.y + threadIdx.y) * CO_CHUNK);

    float acc[CO_CHUNK];
    #pragma unroll
    for (int c = 0; c < CO_CHUNK; ++c) acc[c] = b[c0 + c];

    const int nd = rd ? 1 : 2, nh = rh ? 1 : 2, nw = rw ? 1 : 2;
    for (int td = 0; td < nd; ++td) {
        const int kd = rd ? 1 : (td == 0 ? 2 : 0);
        const int id = rd ? idv : (td == 0 ? idv : idv - 1);
        const bool vd = id >= 0; const int idc = vd ? id : 0;
        for (int th = 0; th < nh; ++th) {
            const int kh = rh ? 1 : (th == 0 ? 2 : 0);
            const int ih = rh ? ihv : (th == 0 ? ihv : ihv - 1);
            const bool vh = ih >= 0; const int ihc = vh ? ih : 0;
            for (int tw = 0; tw < nw; ++tw) {
                const int kw = rw ? 1 : (tw == 0 ? 2 : 0);
                const int iw = rw ? iwv : (tw == 0 ? iwv : iwv - 1);
                const bool vw = iw >= 0; const int iwc = vw ? iw : 0;
                const bool valid = vd && vh && vw;
                const float* __restrict__ xp = x + (size_t)((idc * Din + ihc) * Din + iwc) * Cin;
                const float* __restrict__ wp = w + (size_t)((kd * 3 + kh) * 3 + kw) * Cin * Cout + c0;
                for (int ci = 0; ci < Cin; ci += 4) {
                    float4 xv = *(const float4*)(xp + ci);
                    const float x0 = valid ? xv.x : 0.f;
                    const float x1 = valid ? xv.y : 0.f;
                    const float x2 = valid ? xv.z : 0.f;
                    const float x3 = valid ? xv.w : 0.f;
                    const float* __restrict__ wr = wp + (size_t)ci * Cout;
                    #pragma unroll
                    for (int c = 0; c < CO_CHUNK; ++c) acc[c] = fmaf(x0, wr[c], acc[c]);
                    wr += Cout;
                    #pragma unroll
                    for (int c = 0; c < CO_CHUNK; ++c) acc[c] = fmaf(x1, wr[c], acc[c]);
                    wr += Cout;
                    #pragma unroll
                    for (int c = 0; c < CO_CHUNK; ++c) acc[c] = fmaf(x2, wr[c], acc[c]);
                    wr += Cout;
                    #pragma unroll
                    for (int c = 0; c < CO_CHUNK; ++c) acc[c] = fmaf(x3, wr[c], acc[c]);
                }
            }
        }
    }

    float* __restrict__ yp = y + (size_t)((od * Dout + oh) * Dout + ow) * Cout + c0;
    #pragma unroll
    for (int c = 0; c < CO_CHUNK; c += 4)
        *(float4*)(yp + c) = make_float4(acc[c], acc[c + 1], acc[c + 2], acc[c + 3]);
}

// Final layer: stride 1, Cin=64 -> Cout=3. One thread per voxel, all 3 outputs,
// weights wave-uniform via s_load.
__global__ __launch_bounds__(256) void conv_c3(
    const float* __restrict__ x, const float* __restrict__ w,
    const float* __restrict__ b, float* __restrict__ y, int D, int lD, int Cin)
{
    const int vox = blockIdx.x * blockDim.x + threadIdx.x;
    const int ow = vox & (D - 1);
    const int oh = (vox >> lD) & (D - 1);
    const int od = vox >> (2 * lD);

    float a0 = b[0], a1 = b[1], a2 = b[2];
    for (int kd = 0; kd < 3; ++kd) {
        const int id = od + kd - 1;
        const bool vd = (unsigned)id < (unsigned)D; const int idc = vd ? id : 0;
        for (int kh = 0; kh < 3; ++kh) {
            const int ih = oh + kh - 1;
            const bool vh = (unsigned)ih < (unsigned)D; const int ihc = vh ? ih : 0;
            for (int kw = 0; kw < 3; ++kw) {
                const int iw = ow + kw - 1;
                const bool vw = (unsigned)iw < (unsigned)D; const int iwc = vw ? iw : 0;
                const bool valid = vd && vh && vw;
                const float* __restrict__ xp = x + (size_t)((idc * D + ihc) * D + iwc) * Cin;
                const float* __restrict__ wp = w + (size_t)((kd * 3 + kh) * 3 + kw) * Cin * 3;
                for (int ci = 0; ci < Cin; ci += 4) {
                    float4 xv = *(const float4*)(xp + ci);
                    const float x0 = valid ? xv.x : 0.f;
                    const float x1 = valid ? xv.y : 0.f;
                    const float x2 = valid ? xv.z : 0.f;
                    const float x3 = valid ? xv.w : 0.f;
                    const float* __restrict__ wr = wp + (size_t)ci * 3;
                    a0 = fmaf(x0, wr[0], a0); a1 = fmaf(x0, wr[1], a1); a2 = fmaf(x0, wr[2], a2);
                    a0 = fmaf(x1, wr[3], a0); a1 = fmaf(x1, wr[4], a1); a2 = fmaf(x1, wr[5], a2);
                    a0 = fmaf(x2, wr[6], a0); a1 = fmaf(x2, wr[7], a1); a2 = fmaf(x2, wr[8], a2);
                    a0 = fmaf(x3, wr[9], a0); a1 = fmaf(x3, wr[10], a1); a2 = fmaf(x3, wr[11], a2);
                }
            }
        }
    }
    float* yp = y + (size_t)vox * 3;
    yp[0] = a0; yp[1] = a1; yp[2] = a2;
}

extern "C" void kernel_launch(void* const* d_in, const int* in_sizes, int n_in,
                              void* d_out, int out_size, void* d_ws, size_t ws_size,
                              hipStream_t stream)
{
    const float* x   = (const float*)d_in[0];
    const float* w0  = (const float*)d_in[1];  const float* b0  = (const float*)d_in[2];
    const float* w00 = (const float*)d_in[3];  const float* b00 = (const float*)d_in[4];
    const float* w1  = (const float*)d_in[5];  const float* b1  = (const float*)d_in[6];
    const float* w10 = (const float*)d_in[7];  const float* b10 = (const float*)d_in[8];
    const float* w2  = (const float*)d_in[9];  const float* b2  = (const float*)d_in[10];
    const float* w20 = (const float*)d_in[11]; const float* b20 = (const float*)d_in[12];
    float* out = (float*)d_out;

    // Ping-pong workspace: A(64MB max) / B(16MB max) = 80 MiB total.
    float* A = (float*)d_ws;
    float* B = A + 16777216;

    dim3 blk(64, 4, 1);

    // L0: x(8^3x128) --s2--> A(16^3x128).  8 blocks x (y=4) x (z=8 parity), CO_CHUNK=8.
    deconv_s2<8><<<dim3(8, 4, 8), blk, 0, stream>>>(x, w0, b0, A, 8, 3, 128, 128);
    // L1: A --s1+relu--> B(16^3x128). 64 x 8, CO_CHUNK=4 (more waves for the small grid).
    conv_s1<4, true><<<dim3(64, 8, 1), blk, 0, stream>>>(A, w00, b00, B, 16, 4, 128, 128);
    // L2: B --s2--> A(32^3x128). 64 x 1 x 8, CO_CHUNK=32.
    deconv_s2<32><<<dim3(64, 1, 8), blk, 0, stream>>>(B, w1, b1, A, 16, 4, 128, 128);
    // L3: A --s1+relu--> B(32^3x128). 512 x 1, CO_CHUNK=32.
    conv_s1<32, true><<<dim3(512, 1, 1), blk, 0, stream>>>(A, w10, b10, B, 32, 5, 128, 128);
    // L4: B --s2--> A(64^3x64). 512 x 1 x 8, CO_CHUNK=16.
    deconv_s2<16><<<dim3(512, 1, 8), blk, 0, stream>>>(B, w2, b2, A, 32, 5, 128, 64);
    // L5: A --s1--> out(64^3x3). One thread per voxel.
    conv_c3<<<dim3(1024, 1, 1), dim3(256, 1, 1), 0, stream>>>(A, w20, b20, out, 64, 6, 64);
}

// Round 3
// 2456.687 us; speedup vs baseline: 2.7425x; 1.0749x over previous
//
#include <hip/hip_runtime.h>

// Decoder: 6x conv_transpose3d k=3, NDHWC, fp32.
//   stride 1 SAME: O[o] = sum_k W[k] * X[o+k-1]
//   stride 2 SAME, parity r per dim: r==1 -> tap kd=1,id=i; r==0 -> kd=2,id=i and kd=0,id=i-1.
// Weight layout DHWIO: W[kd][kh][kw][ci][co].
//
// Workspace layout (floats): Z[0,1024) zero page | A = +1024 (16M floats) | B = A+16M (4M floats).
// Invalid taps read the zero page (pointer/offset select once per tap) -> no per-value cndmask.
// Weights/bias are wave-uniform (readfirstlane'd co-group) -> s_load through scalar cache.

__device__ __forceinline__ int rfl(int v) { return __builtin_amdgcn_readfirstlane(v); }
__device__ __forceinline__ float fget(const float4& v, int s) { return ((const float*)&v)[s]; }

__global__ __launch_bounds__(256) void zero4k(float* z) {
    ((float4*)z)[threadIdx.x] = make_float4(0.f, 0.f, 0.f, 0.f);
}

// ---------------- stride-1 conv, VB voxels x CO couts per thread, 64-thread blocks ----------
template<int CO, int VB, bool RELU>
__global__ __launch_bounds__(64) void conv_s1(
    const float* __restrict__ x, const float* __restrict__ w,
    const float* __restrict__ b, float* __restrict__ y, const float* __restrict__ z,
    int D, int lD, int Cin, int Cout)
{
    const int lane = threadIdx.x;
    const int base = blockIdx.x * (64 * VB);
    const int c0   = rfl(blockIdx.y * CO);

    int vv[VB], vw[VB], vh[VB], vd[VB];
    #pragma unroll
    for (int j = 0; j < VB; ++j) {
        vv[j] = base + lane + 64 * j;
        vw[j] = vv[j] & (D - 1);
        vh[j] = (vv[j] >> lD) & (D - 1);
        vd[j] = vv[j] >> (2 * lD);
    }

    float acc[VB * CO];
    #pragma unroll
    for (int j = 0; j < VB; ++j)
        #pragma unroll
        for (int c = 0; c < CO; ++c) acc[j * CO + c] = b[c0 + c];

    for (int kd = 0; kd < 3; ++kd)
    for (int kh = 0; kh < 3; ++kh)
    for (int kw = 0; kw < 3; ++kw) {
        const float* p[VB];
        #pragma unroll
        for (int j = 0; j < VB; ++j) {
            const int id = vd[j] + kd - 1, ih = vh[j] + kh - 1, iw = vw[j] + kw - 1;
            const bool valid = (unsigned)id < (unsigned)D && (unsigned)ih < (unsigned)D &&
                               (unsigned)iw < (unsigned)D;
            p[j] = valid ? x + (size_t)((id * D + ih) * D + iw) * Cin : z;
        }
        const float* __restrict__ wt = w + (size_t)((kd * 3 + kh) * 3 + kw) * Cin * Cout + c0;
        for (int ci = 0; ci < Cin; ci += 4) {
            float4 xv[VB];
            #pragma unroll
            for (int j = 0; j < VB; ++j) xv[j] = *(const float4*)(p[j] + ci);
            const float* __restrict__ wr = wt + ci * Cout;
            #pragma unroll
            for (int s = 0; s < 4; ++s) {
                const float* __restrict__ wrs = wr + s * Cout;
                #pragma unroll
                for (int c = 0; c < CO; ++c) {
                    const float wv = wrs[c];
                    #pragma unroll
                    for (int j = 0; j < VB; ++j)
                        acc[j * CO + c] = fmaf(fget(xv[j], s), wv, acc[j * CO + c]);
                }
            }
        }
    }

    #pragma unroll
    for (int j = 0; j < VB; ++j) {
        float* __restrict__ yp = y + (size_t)vv[j] * Cout + c0;
        #pragma unroll
        for (int c = 0; c < CO; c += 4) {
            float4 o = make_float4(acc[j*CO+c], acc[j*CO+c+1], acc[j*CO+c+2], acc[j*CO+c+3]);
            if (RELU) { o.x=fmaxf(o.x,0.f); o.y=fmaxf(o.y,0.f); o.z=fmaxf(o.z,0.f); o.w=fmaxf(o.w,0.f); }
            *(float4*)(yp + c) = o;
        }
    }
}

// ---------------- stride-2 deconv, parity-decomposed, VB sub-voxels x CO couts -------------
template<int CO, int VB>
__global__ __launch_bounds__(64) void deconv_s2(
    const float* __restrict__ x, const float* __restrict__ w,
    const float* __restrict__ b, float* __restrict__ y, const float* __restrict__ z,
    int Din, int lD, int Cin, int Cout)
{
    const int Dout = 2 * Din;
    const int lane = threadIdx.x;
    const int base = blockIdx.x * (64 * VB);
    const int c0   = rfl(blockIdx.y * CO);
    const int par  = blockIdx.z;
    const int rd = (par >> 2) & 1, rh = (par >> 1) & 1, rw = par & 1;

    int sw[VB], sh[VB], sd[VB];
    #pragma unroll
    for (int j = 0; j < VB; ++j) {
        const int v = base + lane + 64 * j;
        sw[j] = v & (Din - 1);
        sh[j] = (v >> lD) & (Din - 1);
        sd[j] = v >> (2 * lD);
    }

    float acc[VB * CO];
    #pragma unroll
    for (int j = 0; j < VB; ++j)
        #pragma unroll
        for (int c = 0; c < CO; ++c) acc[j * CO + c] = b[c0 + c];

    const int nd = rd ? 1 : 2, nh = rh ? 1 : 2, nw = rw ? 1 : 2;
    for (int td = 0; td < nd; ++td) {
        const int kd = rd ? 1 : (td == 0 ? 2 : 0);
        for (int th = 0; th < nh; ++th) {
            const int kh = rh ? 1 : (th == 0 ? 2 : 0);
            for (int tw = 0; tw < nw; ++tw) {
                const int kw = rw ? 1 : (tw == 0 ? 2 : 0);
                const float* p[VB];
                #pragma unroll
                for (int j = 0; j < VB; ++j) {
                    const int id = rd ? sd[j] : (td == 0 ? sd[j] : sd[j] - 1);
                    const int ih = rh ? sh[j] : (th == 0 ? sh[j] : sh[j] - 1);
                    const int iw = rw ? sw[j] : (tw == 0 ? sw[j] : sw[j] - 1);
                    const bool valid = id >= 0 && ih >= 0 && iw >= 0;
                    p[j] = valid ? x + (size_t)((id * Din + ih) * Din + iw) * Cin : z;
                }
                const float* __restrict__ wt = w + (size_t)((kd * 3 + kh) * 3 + kw) * Cin * Cout + c0;
                for (int ci = 0; ci < Cin; ci += 4) {
                    float4 xv[VB];
                    #pragma unroll
                    for (int j = 0; j < VB; ++j) xv[j] = *(const float4*)(p[j] + ci);
                    const float* __restrict__ wr = wt + ci * Cout;
                    #pragma unroll
                    for (int s = 0; s < 4; ++s) {
                        const float* __restrict__ wrs = wr + s * Cout;
                        #pragma unroll
                        for (int c = 0; c < CO; ++c) {
                            const float wv = wrs[c];
                            #pragma unroll
                            for (int j = 0; j < VB; ++j)
                                acc[j * CO + c] = fmaf(fget(xv[j], s), wv, acc[j * CO + c]);
                        }
                    }
                }
            }
        }
    }

    #pragma unroll
    for (int j = 0; j < VB; ++j) {
        const int od = 2 * sd[j] + rd, oh = 2 * sh[j] + rh, ow = 2 * sw[j] + rw;
        float* __restrict__ yp = y + (size_t)((od * Dout + oh) * Dout + ow) * Cout + c0;
        #pragma unroll
        for (int c = 0; c < CO; c += 4)
            *(float4*)(yp + c) = make_float4(acc[j*CO+c], acc[j*CO+c+1], acc[j*CO+c+2], acc[j*CO+c+3]);
    }
}

// ---------------- final layer: D=64, Cin=64, Cout=3; ci-outer taps-inner, zero-page offsets
__global__ __launch_bounds__(256) void conv_c3z(
    const float* __restrict__ wsb,   // d_ws base; zero page [0,1024), x at +1024
    const float* __restrict__ w, const float* __restrict__ b, float* __restrict__ y)
{
    const int tid = threadIdx.x;
    const int lw = tid & 15, lh = (tid >> 4) & 3, ld = tid >> 6;
    const int bw = blockIdx.x & 3, bh = (blockIdx.x >> 2) & 15, bd = blockIdx.x >> 6;
    const int od = bd * 4 + ld, oh = bh * 4 + lh, ow = bw * 16 + lw;

    int offs[27];
    #pragma unroll
    for (int kd = 0; kd < 3; ++kd)
    #pragma unroll
    for (int kh = 0; kh < 3; ++kh)
    #pragma unroll
    for (int kw = 0; kw < 3; ++kw) {
        const int id = od + kd - 1, ih = oh + kh - 1, iw = ow + kw - 1;
        const bool v = (unsigned)id < 64u && (unsigned)ih < 64u && (unsigned)iw < 64u;
        offs[(kd * 3 + kh) * 3 + kw] = v ? 1024 + ((id * 64 + ih) * 64 + iw) * 64 : 0;
    }

    float a0 = b[0], a1 = b[1], a2 = b[2];
    for (int ci = 0; ci < 64; ci += 4) {
        #pragma unroll
        for (int t = 0; t < 27; ++t) {
            const float4 xv = *(const float4*)(wsb + offs[t] + ci);
            const float* __restrict__ wr = w + t * 192 + ci * 3;
            a0 = fmaf(xv.x, wr[0],  a0); a1 = fmaf(xv.x, wr[1],  a1); a2 = fmaf(xv.x, wr[2],  a2);
            a0 = fmaf(xv.y, wr[3],  a0); a1 = fmaf(xv.y, wr[4],  a1); a2 = fmaf(xv.y, wr[5],  a2);
            a0 = fmaf(xv.z, wr[6],  a0); a1 = fmaf(xv.z, wr[7],  a1); a2 = fmaf(xv.z, wr[8],  a2);
            a0 = fmaf(xv.w, wr[9],  a0); a1 = fmaf(xv.w, wr[10], a1); a2 = fmaf(xv.w, wr[11], a2);
        }
    }
    float* __restrict__ yp = y + ((od * 64 + oh) * 64 + ow) * 3;
    yp[0] = a0; yp[1] = a1; yp[2] = a2;
}

extern "C" void kernel_launch(void* const* d_in, const int* in_sizes, int n_in,
                              void* d_out, int out_size, void* d_ws, size_t ws_size,
                              hipStream_t stream)
{
    const float* x   = (const float*)d_in[0];
    const float* w0  = (const float*)d_in[1];  const float* b0  = (const float*)d_in[2];
    const float* w00 = (const float*)d_in[3];  const float* b00 = (const float*)d_in[4];
    const float* w1  = (const float*)d_in[5];  const float* b1  = (const float*)d_in[6];
    const float* w10 = (const float*)d_in[7];  const float* b10 = (const float*)d_in[8];
    const float* w2  = (const float*)d_in[9];  const float* b2  = (const float*)d_in[10];
    const float* w20 = (const float*)d_in[11]; const float* b20 = (const float*)d_in[12];
    float* out = (float*)d_out;

    float* Z = (float*)d_ws;          // 1024 floats, zeroed each launch
    float* A = Z + 1024;              // up to 16M floats (64 MB)
    float* B = A + 16777216;          // up to 4M floats (16 MB)

    zero4k<<<1, 256, 0, stream>>>(Z);

    // L0: x(8^3 x128) --s2--> A(16^3 x128).   512 sub-voxels, VB=1, CO=8.
    deconv_s2<8, 1><<<dim3(8, 16, 8), 64, 0, stream>>>(x, w0, b0, A, Z, 8, 3, 128, 128);
    // L1: A --s1+relu--> B(16^3 x128). VB=2, CO=4 -> 32x32 = 1024 blocks.
    conv_s1<4, 2, true><<<dim3(32, 32), 64, 0, stream>>>(A, w00, b00, B, Z, 16, 4, 128, 128);
    // L2: B --s2--> A(32^3 x128). VB=2, CO=8 -> 32x16x8 = 4096 blocks.
    deconv_s2<8, 2><<<dim3(32, 16, 8), 64, 0, stream>>>(B, w1, b1, A, Z, 16, 4, 128, 128);
    // L3: A --s1+relu--> B(32^3 x128). VB=4, CO=8 -> 128x16 = 2048 blocks.
    conv_s1<8, 4, true><<<dim3(128, 16), 64, 0, stream>>>(A, w10, b10, B, Z, 32, 5, 128, 128);
    // L4: B --s2--> A(64^3 x64). VB=4, CO=8 -> 128x8x8 = 8192 blocks.
    deconv_s2<8, 4><<<dim3(128, 8, 8), 64, 0, stream>>>(B, w2, b2, A, Z, 32, 5, 128, 64);
    // L5: A --s1--> out(64^3 x3). ci-outer/taps-inner, zero-page offsets. 1024 blocks x 256.
    conv_c3z<<<dim3(1024), 256, 0, stream>>>((const float*)d_ws, w20, b20, out);
}

// Round 4
// 929.219 us; speedup vs baseline: 7.2508x; 2.6438x over previous
//
#include <hip/hip_runtime.h>

// Decoder via bf16 hi/lo-split MFMA implicit GEMM.
//   fp32 v = hi(bf16) + lo(bf16);  A*B ~= Ah*Bh + Ah*Bl + Al*Bh  (3x mfma_f32_16x16x32_bf16)
// conv_transpose SAME:
//   stride1: O[o] = sum_k W[k] X[o+k-1]
//   stride2, parity r: r==1 -> tap kd=1,id=i ; r==0 -> kd=2,id=i and kd=0,id=i-1  (o=2i+r)
// Weights DHWIO [tap][ci][co], activations NDHWC.
// MFMA layouts (verified, learn_hip m89/m120): A[m=lane&15][k=(lane>>4)*8+j],
// B[n=lane&15][k=(lane>>4)*8+j], D: col=lane&15, row=(lane>>4)*4+reg.
//
// Workspace: Z zeros(4KB) | S packed-w hi/lo (1.77MB, rotated per layer) |
//            Q hi/lo (32^3*128 each) | P hi/lo (64^3*64 each).  Total ~85.7 MB.

typedef __attribute__((ext_vector_type(8))) short bf16x8;
typedef __attribute__((ext_vector_type(4))) float f32x4;
typedef unsigned short u16;

__device__ __forceinline__ u16 f2bf(float f) {
    unsigned u = __builtin_bit_cast(unsigned, f);
    u += 0x7fffu + ((u >> 16) & 1u);
    return (u16)(u >> 16);
}
__device__ __forceinline__ float bf2f(u16 h) {
    unsigned u = ((unsigned)h) << 16;
    return __builtin_bit_cast(float, u);
}
__device__ __forceinline__ void split_store(float v, u16* ph, u16* pl) {
    u16 h = f2bf(v);
    *ph = h;
    *pl = f2bf(v - bf2f(h));
}
__device__ __forceinline__ int rfl(int v) { return __builtin_amdgcn_readfirstlane(v); }

__global__ __launch_bounds__(256) void zero4k(float* z) {
    ((float4*)z)[threadIdx.x] = make_float4(0.f, 0.f, 0.f, 0.f);
}

// pack fp32 w[27][Cin][Cout] -> bf16 hi/lo frags, layout [tap][nt][kc][lane][8]
__global__ __launch_bounds__(256) void pack_w(
    const float* __restrict__ w, u16* __restrict__ bh, u16* __restrict__ bl,
    int Cin, int Cout, int nNt)
{
    const int KC = Cin >> 5;
    const int total = 27 * nNt * KC * 64;
    int t = blockIdx.x * 256 + threadIdx.x;
    if (t >= total) return;
    const int lane = t & 63;
    int r = t >> 6;
    const int kc = r % KC; r /= KC;
    const int nt = r % nNt; r /= nNt;
    const int tap = r;
    const int n  = nt * 16 + (lane & 15);
    const int k0 = kc * 32 + (lane >> 4) * 8;
    const size_t o = (size_t)t * 8;
    for (int j = 0; j < 8; ++j) {
        float v = (n < Cout) ? w[((size_t)tap * Cin + k0 + j) * Cout + n] : 0.f;
        u16 h = f2bf(v);
        bh[o + j] = h;
        bl[o + j] = f2bf(v - bf2f(h));
    }
}

// L0: Din=8 (too small for 16-wide m-tiles) -> fp32 VALU, split-store bf16 out.
__global__ __launch_bounds__(64) void deconv_l0(
    const float* __restrict__ x, const float* __restrict__ w,
    const float* __restrict__ b, const float* __restrict__ zf,
    u16* __restrict__ Yh, u16* __restrict__ Yl)
{
    const int lane = threadIdx.x;
    const int sv = blockIdx.x * 64 + lane;
    const int swi = sv & 7, shi = (sv >> 3) & 7, sdi = sv >> 6;
    const int c0 = rfl(blockIdx.y * 8);
    const int par = blockIdx.z;
    const int rd = (par >> 2) & 1, rh = (par >> 1) & 1, rw = par & 1;

    float acc[8];
    #pragma unroll
    for (int c = 0; c < 8; ++c) acc[c] = b[c0 + c];

    const int nd = rd ? 1 : 2, nh = rh ? 1 : 2, nw = rw ? 1 : 2;
    for (int td = 0; td < nd; ++td) {
        const int kd = rd ? 1 : (td ? 0 : 2); const int id = sdi - (rd ? 0 : td);
        for (int th = 0; th < nh; ++th) {
            const int kh = rh ? 1 : (th ? 0 : 2); const int ih = shi - (rh ? 0 : th);
            for (int tw = 0; tw < nw; ++tw) {
                const int kw = rw ? 1 : (tw ? 0 : 2); const int iw = swi - (rw ? 0 : tw);
                const bool valid = id >= 0 && ih >= 0 && iw >= 0;
                const float* __restrict__ p = valid ? x + (size_t)((id * 8 + ih) * 8 + iw) * 128 : zf;
                const float* __restrict__ wt = w + (size_t)((kd * 3 + kh) * 3 + kw) * 128 * 128 + c0;
                for (int ci = 0; ci < 128; ci += 4) {
                    const float4 xv = *(const float4*)(p + ci);
                    const float* __restrict__ wr = wt + (size_t)ci * 128;
                    #pragma unroll
                    for (int s = 0; s < 4; ++s) {
                        const float xs = ((const float*)&xv)[s];
                        const float* __restrict__ wq = wr + s * 128;
                        #pragma unroll
                        for (int c = 0; c < 8; ++c) acc[c] = fmaf(xs, wq[c], acc[c]);
                    }
                }
            }
        }
    }
    const int od = 2 * sdi + rd, oh = 2 * shi + rh, ow = 2 * swi + rw;
    const size_t yo = (size_t)((od * 16 + oh) * 16 + ow) * 128 + c0;
    #pragma unroll
    for (int c = 0; c < 8; ++c) split_store(acc[c], Yh + yo + c, Yl + yo + c);
}

// ---------- stride-1 MFMA conv ----------
template<int CIN, int MT, int NT, bool RELU>
__global__ __launch_bounds__(64) void conv_s1_mfma(
    const u16* __restrict__ Ah, const u16* __restrict__ Al,
    const u16* __restrict__ Bh, const u16* __restrict__ Bl,
    const float* __restrict__ bias, const u16* __restrict__ Z,
    u16* __restrict__ Yh, u16* __restrict__ Yl,
    int D, int lD, int Cout, int nNtTot)
{
    constexpr int KC = CIN >> 5;
    const int lane = threadIdx.x;
    const int ml = lane & 15, kq = lane >> 4;
    const int M0 = blockIdx.x * (MT * 16);
    const int N0t = blockIdx.y * NT;

    int vw[MT], vh[MT], vd[MT];
    #pragma unroll
    for (int mt = 0; mt < MT; ++mt) {
        const int vox = M0 + mt * 16 + ml;
        vw[mt] = vox & (D - 1); vh[mt] = (vox >> lD) & (D - 1); vd[mt] = vox >> (2 * lD);
    }

    f32x4 acc[MT][NT];
    #pragma unroll
    for (int nt = 0; nt < NT; ++nt) {
        const float bv = bias[(N0t + nt) * 16 + ml];
        #pragma unroll
        for (int mt = 0; mt < MT; ++mt) acc[mt][nt] = (f32x4){bv, bv, bv, bv};
    }

    for (int kd = 0; kd < 3; ++kd)
    for (int kh = 0; kh < 3; ++kh)
    for (int kw = 0; kw < 3; ++kw) {
        const int tap = (kd * 3 + kh) * 3 + kw;
        const u16 *pa_h[MT], *pa_l[MT];
        #pragma unroll
        for (int mt = 0; mt < MT; ++mt) {
            const int id = vd[mt] + kd - 1, ih = vh[mt] + kh - 1, iw = vw[mt] + kw - 1;
            const bool v = (unsigned)id < (unsigned)D && (unsigned)ih < (unsigned)D &&
                           (unsigned)iw < (unsigned)D;
            const size_t off = (size_t)((id * D + ih) * D + iw) * CIN;
            pa_h[mt] = v ? Ah + off : Z;
            pa_l[mt] = v ? Al + off : Z;
        }
        const size_t fb = ((size_t)tap * nNtTot + N0t) * KC;
        for (int kc = 0; kc < KC; ++kc) {
            const int ko = kc * 32 + kq * 8;
            bf16x8 ah[MT], al[MT], bh[NT], bl[NT];
            #pragma unroll
            for (int mt = 0; mt < MT; ++mt) {
                ah[mt] = *(const bf16x8*)(pa_h[mt] + ko);
                al[mt] = *(const bf16x8*)(pa_l[mt] + ko);
            }
            #pragma unroll
            for (int nt = 0; nt < NT; ++nt) {
                const size_t fo = (fb + (size_t)nt * KC + kc) * 512 + lane * 8;
                bh[nt] = *(const bf16x8*)(Bh + fo);
                bl[nt] = *(const bf16x8*)(Bl + fo);
            }
            #pragma unroll
            for (int mt = 0; mt < MT; ++mt)
            #pragma unroll
            for (int nt = 0; nt < NT; ++nt) {
                acc[mt][nt] = __builtin_amdgcn_mfma_f32_16x16x32_bf16(ah[mt], bh[nt], acc[mt][nt], 0, 0, 0);
                acc[mt][nt] = __builtin_amdgcn_mfma_f32_16x16x32_bf16(ah[mt], bl[nt], acc[mt][nt], 0, 0, 0);
                acc[mt][nt] = __builtin_amdgcn_mfma_f32_16x16x32_bf16(al[mt], bh[nt], acc[mt][nt], 0, 0, 0);
            }
        }
    }

    #pragma unroll
    for (int mt = 0; mt < MT; ++mt) {
        const int vox0 = M0 + mt * 16 + kq * 4;
        #pragma unroll
        for (int nt = 0; nt < NT; ++nt) {
            const int co = (N0t + nt) * 16 + ml;
            #pragma unroll
            for (int r = 0; r < 4; ++r) {
                float v = acc[mt][nt][r];
                if (RELU) v = fmaxf(v, 0.f);
                const size_t yo = (size_t)(vox0 + r) * Cout + co;
                split_store(v, Yh + yo, Yl + yo);
            }
        }
    }
}

// ---------- stride-2 MFMA deconv (parity-decomposed) ----------
template<int CIN, int MT, int NT>
__global__ __launch_bounds__(64) void deconv_s2_mfma(
    const u16* __restrict__ Ah, const u16* __restrict__ Al,
    const u16* __restrict__ Bh, const u16* __restrict__ Bl,
    const float* __restrict__ bias, const u16* __restrict__ Z,
    u16* __restrict__ Yh, u16* __restrict__ Yl,
    int Din, int lD, int Cout, int nNtTot)
{
    constexpr int KC = CIN >> 5;
    const int Dout = 2 * Din;
    const int lane = threadIdx.x;
    const int ml = lane & 15, kq = lane >> 4;
    const int M0 = blockIdx.x * (MT * 16);
    const int N0t = blockIdx.y * NT;
    const int par = blockIdx.z;
    const int rd = (par >> 2) & 1, rh = (par >> 1) & 1, rw = par & 1;

    int sw[MT], sh[MT], sd[MT];
    #pragma unroll
    for (int mt = 0; mt < MT; ++mt) {
        const int sv = M0 + mt * 16 + ml;
        sw[mt] = sv & (Din - 1); sh[mt] = (sv >> lD) & (Din - 1); sd[mt] = sv >> (2 * lD);
    }

    f32x4 acc[MT][NT];
    #pragma unroll
    for (int nt = 0; nt < NT; ++nt) {
        const float bv = bias[(N0t + nt) * 16 + ml];
        #pragma unroll
        for (int mt = 0; mt < MT; ++mt) acc[mt][nt] = (f32x4){bv, bv, bv, bv};
    }

    const int nd = rd ? 1 : 2, nh = rh ? 1 : 2, nw = rw ? 1 : 2;
    for (int td = 0; td < nd; ++td) {
        const int kd = rd ? 1 : (td ? 0 : 2); const int dd = rd ? 0 : -td;
        for (int th = 0; th < nh; ++th) {
            const int kh = rh ? 1 : (th ? 0 : 2); const int dh = rh ? 0 : -th;
            for (int tw = 0; tw < nw; ++tw) {
                const int kw = rw ? 1 : (tw ? 0 : 2); const int dw = rw ? 0 : -tw;
                const int tap = (kd * 3 + kh) * 3 + kw;
                const u16 *pa_h[MT], *pa_l[MT];
                #pragma unroll
                for (int mt = 0; mt < MT; ++mt) {
                    const int id = sd[mt] + dd, ih = sh[mt] + dh, iw = sw[mt] + dw;
                    const bool v = id >= 0 && ih >= 0 && iw >= 0;
                    const size_t off = (size_t)((id * Din + ih) * Din + iw) * CIN;
                    pa_h[mt] = v ? Ah + off : Z;
                    pa_l[mt] = v ? Al + off : Z;
                }
                const size_t fb = ((size_t)tap * nNtTot + N0t) * KC;
                for (int kc = 0; kc < KC; ++kc) {
                    const int ko = kc * 32 + kq * 8;
                    bf16x8 ah[MT], al[MT], bh[NT], bl[NT];
                    #pragma unroll
                    for (int mt = 0; mt < MT; ++mt) {
                        ah[mt] = *(const bf16x8*)(pa_h[mt] + ko);
                        al[mt] = *(const bf16x8*)(pa_l[mt] + ko);
                    }
                    #pragma unroll
                    for (int nt = 0; nt < NT; ++nt) {
                        const size_t fo = (fb + (size_t)nt * KC + kc) * 512 + lane * 8;
                        bh[nt] = *(const bf16x8*)(Bh + fo);
                        bl[nt] = *(const bf16x8*)(Bl + fo);
                    }
                    #pragma unroll
                    for (int mt = 0; mt < MT; ++mt)
                    #pragma unroll
                    for (int nt = 0; nt < NT; ++nt) {
                        acc[mt][nt] = __builtin_amdgcn_mfma_f32_16x16x32_bf16(ah[mt], bh[nt], acc[mt][nt], 0, 0, 0);
                        acc[mt][nt] = __builtin_amdgcn_mfma_f32_16x16x32_bf16(ah[mt], bl[nt], acc[mt][nt], 0, 0, 0);
                        acc[mt][nt] = __builtin_amdgcn_mfma_f32_16x16x32_bf16(al[mt], bh[nt], acc[mt][nt], 0, 0, 0);
                    }
                }
            }
        }
    }

    #pragma unroll
    for (int mt = 0; mt < MT; ++mt) {
        #pragma unroll
        for (int r = 0; r < 4; ++r) {
            const int sv = M0 + mt * 16 + kq * 4 + r;
            const int svw = sv & (Din - 1), svh = (sv >> lD) & (Din - 1), svd = sv >> (2 * lD);
            const int od = 2 * svd + rd, oh = 2 * svh + rh, ow = 2 * svw + rw;
            const size_t yb = (size_t)((od * Dout + oh) * Dout + ow) * Cout;
            #pragma unroll
            for (int nt = 0; nt < NT; ++nt) {
                const int co = (N0t + nt) * 16 + ml;
                split_store(acc[mt][nt][r], Yh + yb + co, Yl + yb + co);
            }
        }
    }
}

// ---------- final layer: Cin=64 -> Cout=3 (N padded to 16), fp32 out ----------
template<int MT>
__global__ __launch_bounds__(64) void conv_c3_mfma(
    const u16* __restrict__ Ah, const u16* __restrict__ Al,
    const u16* __restrict__ Bh, const u16* __restrict__ Bl,
    const float* __restrict__ bias, const u16* __restrict__ Z,
    float* __restrict__ out)
{
    constexpr int CIN = 64, KC = 2, D = 64, lD = 6;
    const int lane = threadIdx.x;
    const int ml = lane & 15, kq = lane >> 4;
    const int M0 = blockIdx.x * (MT * 16);

    int vw[MT], vh[MT], vd[MT];
    #pragma unroll
    for (int mt = 0; mt < MT; ++mt) {
        const int vox = M0 + mt * 16 + ml;
        vw[mt] = vox & (D - 1); vh[mt] = (vox >> lD) & (D - 1); vd[mt] = vox >> (2 * lD);
    }

    const float bv = (ml < 3) ? bias[ml] : 0.f;
    f32x4 acc[MT];
    #pragma unroll
    for (int mt = 0; mt < MT; ++mt) acc[mt] = (f32x4){bv, bv, bv, bv};

    for (int kd = 0; kd < 3; ++kd)
    for (int kh = 0; kh < 3; ++kh)
    for (int kw = 0; kw < 3; ++kw) {
        const int tap = (kd * 3 + kh) * 3 + kw;
        const u16 *pa_h[MT], *pa_l[MT];
        #pragma unroll
        for (int mt = 0; mt < MT; ++mt) {
            const int id = vd[mt] + kd - 1, ih = vh[mt] + kh - 1, iw = vw[mt] + kw - 1;
            const bool v = (unsigned)id < (unsigned)D && (unsigned)ih < (unsigned)D &&
                           (unsigned)iw < (unsigned)D;
            const size_t off = (size_t)((id * D + ih) * D + iw) * CIN;
            pa_h[mt] = v ? Ah + off : Z;
            pa_l[mt] = v ? Al + off : Z;
        }
        for (int kc = 0; kc < KC; ++kc) {
            const int ko = kc * 32 + kq * 8;
            const size_t fo = ((size_t)tap * KC + kc) * 512 + lane * 8;
            const bf16x8 bh = *(const bf16x8*)(Bh + fo);
            const bf16x8 bl = *(const bf16x8*)(Bl + fo);
            #pragma unroll
            for (int mt = 0; mt < MT; ++mt) {
                const bf16x8 ah = *(const bf16x8*)(pa_h[mt] + ko);
                const bf16x8 al = *(const bf16x8*)(pa_l[mt] + ko);
                acc[mt] = __builtin_amdgcn_mfma_f32_16x16x32_bf16(ah, bh, acc[mt], 0, 0, 0);
                acc[mt] = __builtin_amdgcn_mfma_f32_16x16x32_bf16(ah, bl, acc[mt], 0, 0, 0);
                acc[mt] = __builtin_amdgcn_mfma_f32_16x16x32_bf16(al, bh, acc[mt], 0, 0, 0);
            }
        }
    }

    if (ml < 3) {
        #pragma unroll
        for (int mt = 0; mt < MT; ++mt)
        #pragma unroll
        for (int r = 0; r < 4; ++r)
            out[(size_t)(M0 + mt * 16 + kq * 4 + r) * 3 + ml] = acc[mt][r];
    }
}

extern "C" void kernel_launch(void* const* d_in, const int* in_sizes, int n_in,
                              void* d_out, int out_size, void* d_ws, size_t ws_size,
                              hipStream_t stream)
{
    const float* x   = (const float*)d_in[0];
    const float* w0  = (const float*)d_in[1];  const float* b0  = (const float*)d_in[2];
    const float* w00 = (const float*)d_in[3];  const float* b00 = (const float*)d_in[4];
    const float* w1  = (const float*)d_in[5];  const float* b1  = (const float*)d_in[6];
    const float* w10 = (const float*)d_in[7];  const float* b10 = (const float*)d_in[8];
    const float* w2  = (const float*)d_in[9];  const float* b2  = (const float*)d_in[10];
    const float* w20 = (const float*)d_in[11]; const float* b20 = (const float*)d_in[12];
    float* out = (float*)d_out;

    char* ws = (char*)d_ws;
    float* zf = (float*)ws;                              // 4 KB zero page
    u16*   Z  = (u16*)ws;
    u16*   Sh = (u16*)(ws + 4096);                       // packed weights hi (<=442368 el)
    u16*   Sl = Sh + 442368;                             // packed weights lo
    u16*   Qh = (u16*)(ws + 4096 + 1769472);             // stage Q hi (32^3*128)
    u16*   Ql = Qh + 4194304;
    u16*   Ph = (u16*)(ws + 4096 + 1769472 + 16777216);  // stage P hi (64^3*64)
    u16*   Pl = Ph + 16777216;

    zero4k<<<1, 256, 0, stream>>>(zf);

    // L0: x(8^3x128) --s2 fp32 VALU--> P(16^3x128 hi/lo)
    deconv_l0<<<dim3(8, 16, 8), 64, 0, stream>>>(x, w0, b0, zf, Ph, Pl);

    // L1: P --s1+relu--> Q (D=16). MT=1,NT=2 -> 1024 waves.
    pack_w<<<216, 256, 0, stream>>>(w00, Sh, Sl, 128, 128, 8);
    conv_s1_mfma<128, 1, 2, true><<<dim3(256, 4), 64, 0, stream>>>(
        Ph, Pl, Sh, Sl, b00, Z, Qh, Ql, 16, 4, 128, 8);

    // L2: Q --s2--> P (Din=16). MT=2,NT=4 -> 2048 waves.
    pack_w<<<216, 256, 0, stream>>>(w1, Sh, Sl, 128, 128, 8);
    deconv_s2_mfma<128, 2, 4><<<dim3(128, 2, 8), 64, 0, stream>>>(
        Qh, Ql, Sh, Sl, b1, Z, Ph, Pl, 16, 4, 128, 8);

    // L3: P --s1+relu--> Q (D=32). MT=2,NT=4 -> 2048 waves.
    pack_w<<<216, 256, 0, stream>>>(w10, Sh, Sl, 128, 128, 8);
    conv_s1_mfma<128, 2, 4, true><<<dim3(1024, 2), 64, 0, stream>>>(
        Ph, Pl, Sh, Sl, b10, Z, Qh, Ql, 32, 5, 128, 8);

    // L4: Q --s2--> P (Din=32, Cout=64). MT=2,NT=4 -> 8192 waves.
    pack_w<<<108, 256, 0, stream>>>(w2, Sh, Sl, 128, 64, 4);
    deconv_s2_mfma<128, 2, 4><<<dim3(1024, 1, 8), 64, 0, stream>>>(
        Qh, Ql, Sh, Sl, b2, Z, Ph, Pl, 32, 5, 64, 4);

    // L5: P --s1--> out (D=64, Cin=64, Cout=3 padded to 16). MT=4 -> 4096 waves.
    pack_w<<<14, 256, 0, stream>>>(w20, Sh, Sl, 64, 3, 1);
    conv_c3_mfma<4><<<dim3(4096), 64, 0, stream>>>(Ph, Pl, Sh, Sl, b20, Z, out);
}

// Round 5
// 624.365 us; speedup vs baseline: 10.7910x; 1.4883x over previous
//
#include <hip/hip_runtime.h>

// Decoder via bf16 hi/lo-split MFMA implicit GEMM.
//   fp32 v = hi(bf16) + lo(bf16);  A*B ~= Ah*Bh + Ah*Bl + Al*Bh  (3x mfma_f32_16x16x32_bf16)
// conv_transpose SAME:
//   stride1: O[o] = sum_k W[k] X[o+k-1]
//   stride2, parity r: r==1 -> tap kd=1,id=i ; r==0 -> kd=2,id=i and kd=0,id=i-1  (o=2i+r)
// Weights DHWIO [tap][ci][co], activations NDHWC.
// MFMA layouts (verified): A[m=lane&15][k=(lane>>4)*8+j], B[n=lane&15][k=(lane>>4)*8+j],
// D: col=lane&15, row=(lane>>4)*4+reg.
//
// Round5: XCD-aware swizzle (round-robin dispatch puts consecutive blockIdx on different
// XCDs; remap so each XCD owns a contiguous d-slab -> tap halo reuse lands in per-XCD L2),
// L5 stages A-hi halo rows in LDS (guaranteed reuse), MT=4 on L3/L4.

typedef __attribute__((ext_vector_type(8))) short bf16x8;
typedef __attribute__((ext_vector_type(4))) float f32x4;
typedef unsigned short u16;

__device__ __forceinline__ u16 f2bf(float f) {
    unsigned u = __builtin_bit_cast(unsigned, f);
    u += 0x7fffu + ((u >> 16) & 1u);
    return (u16)(u >> 16);
}
__device__ __forceinline__ float bf2f(u16 h) {
    unsigned u = ((unsigned)h) << 16;
    return __builtin_bit_cast(float, u);
}
__device__ __forceinline__ void split_store(float v, u16* ph, u16* pl) {
    u16 h = f2bf(v);
    *ph = h;
    *pl = f2bf(v - bf2f(h));
}
__device__ __forceinline__ int rfl(int v) { return __builtin_amdgcn_readfirstlane(v); }
// XCD swizzle: physical bx -> logical block, giving each XCD a contiguous range.
__device__ __forceinline__ int swz(int bx, int G) { return (bx & 7) * (G >> 3) + (bx >> 3); }

__global__ __launch_bounds__(256) void zero4k(float* z) {
    ((float4*)z)[threadIdx.x] = make_float4(0.f, 0.f, 0.f, 0.f);
}

// pack fp32 w[27][Cin][Cout] -> bf16 hi/lo frags, layout [tap][nt][kc][lane][8]
__global__ __launch_bounds__(256) void pack_w(
    const float* __restrict__ w, u16* __restrict__ bh, u16* __restrict__ bl,
    int Cin, int Cout, int nNt)
{
    const int KC = Cin >> 5;
    const int total = 27 * nNt * KC * 64;
    int t = blockIdx.x * 256 + threadIdx.x;
    if (t >= total) return;
    const int lane = t & 63;
    int r = t >> 6;
    const int kc = r % KC; r /= KC;
    const int nt = r % nNt; r /= nNt;
    const int tap = r;
    const int n  = nt * 16 + (lane & 15);
    const int k0 = kc * 32 + (lane >> 4) * 8;
    const size_t o = (size_t)t * 8;
    for (int j = 0; j < 8; ++j) {
        float v = (n < Cout) ? w[((size_t)tap * Cin + k0 + j) * Cout + n] : 0.f;
        u16 h = f2bf(v);
        bh[o + j] = h;
        bl[o + j] = f2bf(v - bf2f(h));
    }
}

// L0: Din=8 -> fp32 VALU, split-store bf16 out.
__global__ __launch_bounds__(64) void deconv_l0(
    const float* __restrict__ x, const float* __restrict__ w,
    const float* __restrict__ b, const float* __restrict__ zf,
    u16* __restrict__ Yh, u16* __restrict__ Yl)
{
    const int lane = threadIdx.x;
    const int sv = blockIdx.x * 64 + lane;
    const int swi = sv & 7, shi = (sv >> 3) & 7, sdi = sv >> 6;
    const int c0 = rfl(blockIdx.y * 8);
    const int par = blockIdx.z;
    const int rd = (par >> 2) & 1, rh = (par >> 1) & 1, rw = par & 1;

    float acc[8];
    #pragma unroll
    for (int c = 0; c < 8; ++c) acc[c] = b[c0 + c];

    const int nd = rd ? 1 : 2, nh = rh ? 1 : 2, nw = rw ? 1 : 2;
    for (int td = 0; td < nd; ++td) {
        const int kd = rd ? 1 : (td ? 0 : 2); const int id = sdi - (rd ? 0 : td);
        for (int th = 0; th < nh; ++th) {
            const int kh = rh ? 1 : (th ? 0 : 2); const int ih = shi - (rh ? 0 : th);
            for (int tw = 0; tw < nw; ++tw) {
                const int kw = rw ? 1 : (tw ? 0 : 2); const int iw = swi - (rw ? 0 : tw);
                const bool valid = id >= 0 && ih >= 0 && iw >= 0;
                const float* __restrict__ p = valid ? x + (size_t)((id * 8 + ih) * 8 + iw) * 128 : zf;
                const float* __restrict__ wt = w + (size_t)((kd * 3 + kh) * 3 + kw) * 128 * 128 + c0;
                for (int ci = 0; ci < 128; ci += 4) {
                    const float4 xv = *(const float4*)(p + ci);
                    const float* __restrict__ wr = wt + (size_t)ci * 128;
                    #pragma unroll
                    for (int s = 0; s < 4; ++s) {
                        const float xs = ((const float*)&xv)[s];
                        const float* __restrict__ wq = wr + s * 128;
                        #pragma unroll
                        for (int c = 0; c < 8; ++c) acc[c] = fmaf(xs, wq[c], acc[c]);
                    }
                }
            }
        }
    }
    const int od = 2 * sdi + rd, oh = 2 * shi + rh, ow = 2 * swi + rw;
    const size_t yo = (size_t)((od * 16 + oh) * 16 + ow) * 128 + c0;
    #pragma unroll
    for (int c = 0; c < 8; ++c) split_store(acc[c], Yh + yo + c, Yl + yo + c);
}

// ---------- stride-1 MFMA conv ----------
template<int CIN, int MT, int NT, bool RELU>
__global__ __launch_bounds__(64) void conv_s1_mfma(
    const u16* __restrict__ Ah, const u16* __restrict__ Al,
    const u16* __restrict__ Bh, const u16* __restrict__ Bl,
    const float* __restrict__ bias, const u16* __restrict__ Z,
    u16* __restrict__ Yh, u16* __restrict__ Yl,
    int D, int lD, int Cout, int nNtTot)
{
    constexpr int KC = CIN >> 5;
    const int lane = threadIdx.x;
    const int ml = lane & 15, kq = lane >> 4;
    const int M0 = swz(blockIdx.x, gridDim.x) * (MT * 16);
    const int N0t = blockIdx.y * NT;

    int vw[MT], vh[MT], vd[MT];
    #pragma unroll
    for (int mt = 0; mt < MT; ++mt) {
        const int vox = M0 + mt * 16 + ml;
        vw[mt] = vox & (D - 1); vh[mt] = (vox >> lD) & (D - 1); vd[mt] = vox >> (2 * lD);
    }

    f32x4 acc[MT][NT];
    #pragma unroll
    for (int nt = 0; nt < NT; ++nt) {
        const float bv = bias[(N0t + nt) * 16 + ml];
        #pragma unroll
        for (int mt = 0; mt < MT; ++mt) acc[mt][nt] = (f32x4){bv, bv, bv, bv};
    }

    for (int kd = 0; kd < 3; ++kd)
    for (int kh = 0; kh < 3; ++kh)
    for (int kw = 0; kw < 3; ++kw) {
        const int tap = (kd * 3 + kh) * 3 + kw;
        const u16 *pa_h[MT], *pa_l[MT];
        #pragma unroll
        for (int mt = 0; mt < MT; ++mt) {
            const int id = vd[mt] + kd - 1, ih = vh[mt] + kh - 1, iw = vw[mt] + kw - 1;
            const bool v = (unsigned)id < (unsigned)D && (unsigned)ih < (unsigned)D &&
                           (unsigned)iw < (unsigned)D;
            const size_t off = (size_t)((id * D + ih) * D + iw) * CIN;
            pa_h[mt] = v ? Ah + off : Z;
            pa_l[mt] = v ? Al + off : Z;
        }
        const size_t fb = ((size_t)tap * nNtTot + N0t) * KC;
        for (int kc = 0; kc < KC; ++kc) {
            const int ko = kc * 32 + kq * 8;
            bf16x8 ah[MT], al[MT], bh[NT], bl[NT];
            #pragma unroll
            for (int mt = 0; mt < MT; ++mt) {
                ah[mt] = *(const bf16x8*)(pa_h[mt] + ko);
                al[mt] = *(const bf16x8*)(pa_l[mt] + ko);
            }
            #pragma unroll
            for (int nt = 0; nt < NT; ++nt) {
                const size_t fo = (fb + (size_t)nt * KC + kc) * 512 + lane * 8;
                bh[nt] = *(const bf16x8*)(Bh + fo);
                bl[nt] = *(const bf16x8*)(Bl + fo);
            }
            #pragma unroll
            for (int mt = 0; mt < MT; ++mt)
            #pragma unroll
            for (int nt = 0; nt < NT; ++nt) {
                acc[mt][nt] = __builtin_amdgcn_mfma_f32_16x16x32_bf16(ah[mt], bh[nt], acc[mt][nt], 0, 0, 0);
                acc[mt][nt] = __builtin_amdgcn_mfma_f32_16x16x32_bf16(ah[mt], bl[nt], acc[mt][nt], 0, 0, 0);
                acc[mt][nt] = __builtin_amdgcn_mfma_f32_16x16x32_bf16(al[mt], bh[nt], acc[mt][nt], 0, 0, 0);
            }
        }
    }

    #pragma unroll
    for (int mt = 0; mt < MT; ++mt) {
        const int vox0 = M0 + mt * 16 + kq * 4;
        #pragma unroll
        for (int nt = 0; nt < NT; ++nt) {
            const int co = (N0t + nt) * 16 + ml;
            #pragma unroll
            for (int r = 0; r < 4; ++r) {
                float v = acc[mt][nt][r];
                if (RELU) v = fmaxf(v, 0.f);
                const size_t yo = (size_t)(vox0 + r) * Cout + co;
                split_store(v, Yh + yo, Yl + yo);
            }
        }
    }
}

// ---------- stride-2 MFMA deconv (parity-decomposed) ----------
template<int CIN, int MT, int NT>
__global__ __launch_bounds__(64) void deconv_s2_mfma(
    const u16* __restrict__ Ah, const u16* __restrict__ Al,
    const u16* __restrict__ Bh, const u16* __restrict__ Bl,
    const float* __restrict__ bias, const u16* __restrict__ Z,
    u16* __restrict__ Yh, u16* __restrict__ Yl,
    int Din, int lD, int Cout, int nNtTot)
{
    constexpr int KC = CIN >> 5;
    const int Dout = 2 * Din;
    const int lane = threadIdx.x;
    const int ml = lane & 15, kq = lane >> 4;
    const int M0 = swz(blockIdx.x, gridDim.x) * (MT * 16);
    const int N0t = blockIdx.y * NT;
    const int par = blockIdx.z;
    const int rd = (par >> 2) & 1, rh = (par >> 1) & 1, rw = par & 1;

    int sw[MT], sh[MT], sd[MT];
    #pragma unroll
    for (int mt = 0; mt < MT; ++mt) {
        const int sv = M0 + mt * 16 + ml;
        sw[mt] = sv & (Din - 1); sh[mt] = (sv >> lD) & (Din - 1); sd[mt] = sv >> (2 * lD);
    }

    f32x4 acc[MT][NT];
    #pragma unroll
    for (int nt = 0; nt < NT; ++nt) {
        const float bv = bias[(N0t + nt) * 16 + ml];
        #pragma unroll
        for (int mt = 0; mt < MT; ++mt) acc[mt][nt] = (f32x4){bv, bv, bv, bv};
    }

    const int nd = rd ? 1 : 2, nh = rh ? 1 : 2, nw = rw ? 1 : 2;
    for (int td = 0; td < nd; ++td) {
        const int kd = rd ? 1 : (td ? 0 : 2); const int dd = rd ? 0 : -td;
        for (int th = 0; th < nh; ++th) {
            const int kh = rh ? 1 : (th ? 0 : 2); const int dh = rh ? 0 : -th;
            for (int tw = 0; tw < nw; ++tw) {
                const int kw = rw ? 1 : (tw ? 0 : 2); const int dw = rw ? 0 : -tw;
                const int tap = (kd * 3 + kh) * 3 + kw;
                const u16 *pa_h[MT], *pa_l[MT];
                #pragma unroll
                for (int mt = 0; mt < MT; ++mt) {
                    const int id = sd[mt] + dd, ih = sh[mt] + dh, iw = sw[mt] + dw;
                    const bool v = id >= 0 && ih >= 0 && iw >= 0;
                    const size_t off = (size_t)((id * Din + ih) * Din + iw) * CIN;
                    pa_h[mt] = v ? Ah + off : Z;
                    pa_l[mt] = v ? Al + off : Z;
                }
                const size_t fb = ((size_t)tap * nNtTot + N0t) * KC;
                for (int kc = 0; kc < KC; ++kc) {
                    const int ko = kc * 32 + kq * 8;
                    bf16x8 ah[MT], al[MT], bh[NT], bl[NT];
                    #pragma unroll
                    for (int mt = 0; mt < MT; ++mt) {
                        ah[mt] = *(const bf16x8*)(pa_h[mt] + ko);
                        al[mt] = *(const bf16x8*)(pa_l[mt] + ko);
                    }
                    #pragma unroll
                    for (int nt = 0; nt < NT; ++nt) {
                        const size_t fo = (fb + (size_t)nt * KC + kc) * 512 + lane * 8;
                        bh[nt] = *(const bf16x8*)(Bh + fo);
                        bl[nt] = *(const bf16x8*)(Bl + fo);
                    }
                    #pragma unroll
                    for (int mt = 0; mt < MT; ++mt)
                    #pragma unroll
                    for (int nt = 0; nt < NT; ++nt) {
                        acc[mt][nt] = __builtin_amdgcn_mfma_f32_16x16x32_bf16(ah[mt], bh[nt], acc[mt][nt], 0, 0, 0);
                        acc[mt][nt] = __builtin_amdgcn_mfma_f32_16x16x32_bf16(ah[mt], bl[nt], acc[mt][nt], 0, 0, 0);
                        acc[mt][nt] = __builtin_amdgcn_mfma_f32_16x16x32_bf16(al[mt], bh[nt], acc[mt][nt], 0, 0, 0);
                    }
                }
            }
        }
    }

    #pragma unroll
    for (int mt = 0; mt < MT; ++mt) {
        #pragma unroll
        for (int r = 0; r < 4; ++r) {
            const int sv = M0 + mt * 16 + kq * 4 + r;
            const int svw = sv & (Din - 1), svh = (sv >> lD) & (Din - 1), svd = sv >> (2 * lD);
            const int od = 2 * svd + rd, oh = 2 * svh + rh, ow = 2 * svw + rw;
            const size_t yb = (size_t)((od * Dout + oh) * Dout + ow) * Cout;
            #pragma unroll
            for (int nt = 0; nt < NT; ++nt) {
                const int co = (N0t + nt) * 16 + ml;
                split_store(acc[mt][nt][r], Yh + yb + co, Yl + yb + co);
            }
        }
    }
}

// ---------- final layer: D=64, Cin=64 -> Cout=3 (N pad 16), LDS-staged A-hi ----------
// Block: 256 threads = 4 waves, covers rows (d, h0..h0+3), full w. Per kd, the 6 halo
// rows of plane d+kd-1 are staged (hi) in LDS once; lo comes from global (L2/swizzle).
#define L5_VST 72                 // u16 per voxel slot: 64 ch + 8 pad (breaks 16-way banks)
#define L5_RST (66 * L5_VST)      // row stride in u16 (66 vox: 1+64+1 edge pads)
__global__ __launch_bounds__(256) void conv_c3_lds(
    const u16* __restrict__ Ah, const u16* __restrict__ Al,
    const u16* __restrict__ Bh, const u16* __restrict__ Bl,
    const float* __restrict__ bias, const u16* __restrict__ Z,
    float* __restrict__ out)
{
    __shared__ u16 sm[6 * L5_RST];      // 57,024 B

    const int tid  = threadIdx.x;
    const int lane = tid & 63, widx = tid >> 6;
    const int ml = lane & 15, kq = lane >> 4;

    const int lb = swz(blockIdx.x, gridDim.x);   // 1024 blocks: d = lb>>4, hgrp = lb&15
    const int d  = lb >> 4;
    const int h0 = (lb & 15) * 4;
    const int h  = h0 + widx;

    const float bv = (ml < 3) ? bias[ml] : 0.f;
    f32x4 acc[4];
    #pragma unroll
    for (int mt = 0; mt < 4; ++mt) acc[mt] = (f32x4){bv, bv, bv, bv};

    for (int kd = 0; kd < 3; ++kd) {
        const int pd = d + kd - 1;
        const bool vpd = (unsigned)pd < 64u;
        __syncthreads();
        // stage 6 hi-rows (hh = h0-1 .. h0+4) of plane pd; 3072 16B-chunks over 256 threads
        for (int i = 0; i < 12; ++i) {
            const int c = tid + 256 * i;          // [0,3072)
            const int r = c >> 9;                 // row slot 0..5
            const int rem = c & 511;
            const int vox = rem >> 3, ch8 = rem & 7;
            const int hh = h0 - 1 + r;
            u16* dst = sm + r * L5_RST + (vox + 1) * L5_VST + ch8 * 8;
            if (vpd && (unsigned)hh < 64u) {
                const u16* src = Ah + ((size_t)((pd * 64 + hh) * 64 + vox) * 64 + ch8 * 8);
                *(bf16x8*)dst = *(const bf16x8*)src;
            } else {
                *(bf16x8*)dst = (bf16x8){0,0,0,0,0,0,0,0};
            }
        }
        // zero the w-edge pad voxels (slots 0 and 65): 6 rows x 2 x 8 chunks = 96
        if (tid < 96) {
            const int r = tid >> 4, side = (tid >> 3) & 1, ch8 = tid & 7;
            *(bf16x8*)(sm + r * L5_RST + (side ? 65 : 0) * L5_VST + ch8 * 8) =
                (bf16x8){0,0,0,0,0,0,0,0};
        }
        __syncthreads();

        for (int kh = 0; kh < 3; ++kh) {
            const int slot = widx + kh;           // LDS row slot for (h + kh - 1)
            const int hh = h + kh - 1;
            const bool vrow = vpd && (unsigned)hh < 64u;
            const size_t rowoff = (size_t)((pd * 64 + hh) * 64) * 64;
            for (int kw = 0; kw < 3; ++kw) {
                const int tap = (kd * 3 + kh) * 3 + kw;
                #pragma unroll
                for (int kc = 0; kc < 2; ++kc) {
                    const int ko = kc * 32 + kq * 8;
                    const size_t fo = ((size_t)tap * 2 + kc) * 512 + lane * 8;
                    const bf16x8 bhf = *(const bf16x8*)(Bh + fo);
                    const bf16x8 blf = *(const bf16x8*)(Bl + fo);
                    #pragma unroll
                    for (int mt = 0; mt < 4; ++mt) {
                        const int m = ml + 16 * mt;
                        const bf16x8 ahf = *(const bf16x8*)(sm + slot * L5_RST +
                                                            (m + kw) * L5_VST + ko);
                        const int v = m + kw - 1;
                        const bool vv = vrow && (unsigned)v < 64u;
                        const u16* lp = vv ? Al + rowoff + (size_t)v * 64 : Z;
                        const bf16x8 alf = *(const bf16x8*)(lp + ko);
                        acc[mt] = __builtin_amdgcn_mfma_f32_16x16x32_bf16(ahf, bhf, acc[mt], 0, 0, 0);
                        acc[mt] = __builtin_amdgcn_mfma_f32_16x16x32_bf16(ahf, blf, acc[mt], 0, 0, 0);
                        acc[mt] = __builtin_amdgcn_mfma_f32_16x16x32_bf16(alf, bhf, acc[mt], 0, 0, 0);
                    }
                }
            }
        }
    }

    if (ml < 3) {
        const size_t vb = (size_t)(d * 64 + h) * 64;
        #pragma unroll
        for (int mt = 0; mt < 4; ++mt)
        #pragma unroll
        for (int r = 0; r < 4; ++r)
            out[(vb + mt * 16 + kq * 4 + r) * 3 + ml] = acc[mt][r];
    }
}

extern "C" void kernel_launch(void* const* d_in, const int* in_sizes, int n_in,
                              void* d_out, int out_size, void* d_ws, size_t ws_size,
                              hipStream_t stream)
{
    const float* x   = (const float*)d_in[0];
    const float* w0  = (const float*)d_in[1];  const float* b0  = (const float*)d_in[2];
    const float* w00 = (const float*)d_in[3];  const float* b00 = (const float*)d_in[4];
    const float* w1  = (const float*)d_in[5];  const float* b1  = (const float*)d_in[6];
    const float* w10 = (const float*)d_in[7];  const float* b10 = (const float*)d_in[8];
    const float* w2  = (const float*)d_in[9];  const float* b2  = (const float*)d_in[10];
    const float* w20 = (const float*)d_in[11]; const float* b20 = (const float*)d_in[12];
    float* out = (float*)d_out;

    char* ws = (char*)d_ws;
    float* zf = (float*)ws;                              // 4 KB zero page
    u16*   Z  = (u16*)ws;
    u16*   Sh = (u16*)(ws + 4096);                       // packed weights hi
    u16*   Sl = Sh + 442368;                             // packed weights lo
    u16*   Qh = (u16*)(ws + 4096 + 1769472);             // Q hi (32^3*128)
    u16*   Ql = Qh + 4194304;
    u16*   Ph = (u16*)(ws + 4096 + 1769472 + 16777216);  // P hi (64^3*64 / 16^3*128)
    u16*   Pl = Ph + 16777216;

    zero4k<<<1, 256, 0, stream>>>(zf);

    // L0: x(8^3x128) --s2 fp32 VALU--> P(16^3x128 hi/lo)
    deconv_l0<<<dim3(8, 16, 8), 64, 0, stream>>>(x, w0, b0, zf, Ph, Pl);

    // L1: P --s1+relu--> Q (D=16). MT=1,NT=2.
    pack_w<<<216, 256, 0, stream>>>(w00, Sh, Sl, 128, 128, 8);
    conv_s1_mfma<128, 1, 2, true><<<dim3(256, 4), 64, 0, stream>>>(
        Ph, Pl, Sh, Sl, b00, Z, Qh, Ql, 16, 4, 128, 8);

    // L2: Q --s2--> P (Din=16). MT=2,NT=4.
    pack_w<<<216, 256, 0, stream>>>(w1, Sh, Sl, 128, 128, 8);
    deconv_s2_mfma<128, 2, 4><<<dim3(128, 2, 8), 64, 0, stream>>>(
        Qh, Ql, Sh, Sl, b1, Z, Ph, Pl, 16, 4, 128, 8);

    // L3: P --s1+relu--> Q (D=32). MT=4,NT=4 (block = 2 full h-rows).
    pack_w<<<216, 256, 0, stream>>>(w10, Sh, Sl, 128, 128, 8);
    conv_s1_mfma<128, 4, 4, true><<<dim3(512, 2), 64, 0, stream>>>(
        Ph, Pl, Sh, Sl, b10, Z, Qh, Ql, 32, 5, 128, 8);

    // L4: Q --s2--> P (Din=32, Cout=64). MT=4,NT=4.
    pack_w<<<108, 256, 0, stream>>>(w2, Sh, Sl, 128, 64, 4);
    deconv_s2_mfma<128, 4, 4><<<dim3(512, 1, 8), 64, 0, stream>>>(
        Qh, Ql, Sh, Sl, b2, Z, Ph, Pl, 32, 5, 64, 4);

    // L5: P --s1--> out (D=64, Cin=64, Cout=3 pad 16). LDS-staged, 1024 blocks x 256.
    pack_w<<<14, 256, 0, stream>>>(w20, Sh, Sl, 64, 3, 1);
    conv_c3_lds<<<dim3(1024), 256, 0, stream>>>(Ph, Pl, Sh, Sl, b20, Z, out);
}